// Round 6
// baseline (425.569 us; speedup 1.0000x reference)
//
#include <hip/hip_runtime.h>

typedef __bf16 bf16x8 __attribute__((ext_vector_type(8)));
typedef float f32x4 __attribute__((ext_vector_type(4)));

__device__ __forceinline__ unsigned short f2bf(float f) {
  unsigned u = __builtin_bit_cast(unsigned, f);
  u += 0x7fffu + ((u >> 16) & 1u);
  return (unsigned short)(u >> 16);
}
__device__ __forceinline__ float bf2f(unsigned short h) {
  unsigned u = ((unsigned)h) << 16;
  return __builtin_bit_cast(float, u);
}
__device__ __forceinline__ void gload16(const void* g, void* l) {
  __builtin_amdgcn_global_load_lds((const __attribute__((address_space(1))) void*)g,
                                   (__attribute__((address_space(3))) void*)l, 16, 0, 0);
}

// ---------------- phase A ----------------

// xmn[b,t,k] = mean_n x[b,:,t,k]
__global__ __launch_bounds__(256) void k_xmn(const float* __restrict__ x, float* __restrict__ xmn) {
  int b = blockIdx.x / 12, t = blockIdx.x % 12;
  int k = threadIdx.x & 31, sl = threadIdx.x >> 5;
  const float* xp = x + (size_t)b * 786432 + (size_t)t * 32 + k;
  float s = 0.f;
  for (int i = 0; i < 256; ++i) {
    int n = (sl << 8) + i;
    s += xp[(size_t)n * 384];
  }
  __shared__ float red[8][32];
  red[sl][k] = s;
  __syncthreads();
  if (threadIdx.x < 32) {
    float tot = 0.f;
#pragma unroll
    for (int j = 0; j < 8; ++j) tot += red[j][threadIdx.x];
    xmn[(b * 12 + t) * 32 + threadIdx.x] = tot * (1.0f / 2048.0f);
  }
}

// Fused: per block (4 n-values): mean_t(x) -> @W_Q0 -> contract with W_QS rows
__global__ __launch_bounds__(256) void k_qs(const float* __restrict__ x,
                                            const float* __restrict__ W_Q0,
                                            const float* __restrict__ W_QS,
                                            float* __restrict__ pqs) {
  __shared__ __align__(16) float w0[1024];
  __shared__ float lm[2048];
  __shared__ float lq[2048];
  __shared__ float red[4][16][64];
  int tid = threadIdx.x;
#pragma unroll
  for (int i = 0; i < 4; ++i) w0[tid + i * 256] = W_Q0[tid + i * 256];
  int n0 = blockIdx.x * 4;
#pragma unroll
  for (int j = 0; j < 8; ++j) {
    int i = tid + j * 256;
    int b = i >> 7, r = i & 127;
    int n = n0 + (r >> 5), k = r & 31;
    const float* xp = x + ((size_t)(b * 2048 + n) * 12) * 32 + k;
    float s = 0.f;
#pragma unroll
    for (int t = 0; t < 12; ++t) s += xp[t * 32];
    lm[i] = s * (1.0f / 12.0f);
  }
  __syncthreads();
#pragma unroll
  for (int j = 0; j < 8; ++j) {
    int i = tid + j * 256;
    int br = i >> 5, q = i & 31;
    const float* mrow = &lm[br * 32];
    float a = 0.f;
#pragma unroll
    for (int k = 0; k < 32; ++k) a += mrow[k] * w0[k * 32 + q];
    lq[i] = a;
  }
  __syncthreads();
  int lane = tid & 63, wid = tid >> 6;
  float acc[16];
#pragma unroll
  for (int b = 0; b < 16; ++b) acc[b] = 0.f;
  for (int rl = 0; rl < 32; ++rl) {
    int r = wid * 32 + rl;
    float wv = W_QS[(size_t)(n0 * 32 + r) * 64 + lane];
#pragma unroll
    for (int b = 0; b < 16; ++b) acc[b] += lq[b * 128 + r] * wv;
  }
#pragma unroll
  for (int b = 0; b < 16; ++b) red[wid][b][lane] = acc[b];
  __syncthreads();
#pragma unroll
  for (int it = 0; it < 4; ++it) {
    int idx = tid + it * 256;
    float s = red[0][idx >> 6][idx & 63] + red[1][idx >> 6][idx & 63] +
              red[2][idx >> 6][idx & 63] + red[3][idx >> 6][idx & 63];
    pqs[(size_t)blockIdx.x * 1024 + idx] = s;
  }
}

// Fused tail: qs-reduce + qt + attn + ets  (one block per batch b)
__global__ __launch_bounds__(256) void k_post(const float* __restrict__ pqs,
                                              const float* __restrict__ xmn,
                                              const float* __restrict__ W_Q0,
                                              const float* __restrict__ W_QT,
                                              const float* __restrict__ K_T,
                                              const float* __restrict__ K_S,
                                              const float* __restrict__ V_T,
                                              const float* __restrict__ V_S,
                                              unsigned short* __restrict__ ets_bf) {
  const int b = blockIdx.x, tid = threadIdx.x;
  __shared__ float red[4][64];
  __shared__ float qs_s[64];
  __shared__ float qt_s[64];
  __shared__ float xp[384];
  __shared__ float at_s[8];

  {
    float s = 0.f;
    for (int c = tid >> 6; c < 512; c += 4) s += pqs[(size_t)c * 1024 + b * 64 + (tid & 63)];
    red[tid >> 6][tid & 63] = s;
  }
  for (int i = tid; i < 384; i += 256) {
    int t = i >> 5, q = i & 31;
    float a = 0.f;
#pragma unroll
    for (int k = 0; k < 32; ++k) a += xmn[(b * 12 + t) * 32 + k] * W_Q0[k * 32 + q];
    xp[i] = a;
  }
  __syncthreads();
  if (tid < 64) qs_s[tid] = red[0][tid] + red[1][tid] + red[2][tid] + red[3][tid];
  __syncthreads();
  if (tid < 64) {
    float q = 0.f;
    for (int i = 0; i < 384; ++i) q += xp[i] * W_QT[i * 64 + tid];
    qt_s[tid] = q;
  }
  __syncthreads();
  if (tid < 64) {
    int lane = tid;
    float qsv = qs_s[lane], qtv = qt_s[lane];
    float lt[4], ls[4];
#pragma unroll
    for (int h = 0; h < 4; ++h) {
      float p = qtv * K_T[h * 64 + lane];
#pragma unroll
      for (int off = 32; off > 0; off >>= 1) p += __shfl_xor(p, off);
      lt[h] = p;
      float p2 = qsv * K_S[h * 64 + lane];
#pragma unroll
      for (int off = 32; off > 0; off >>= 1) p2 += __shfl_xor(p2, off);
      ls[h] = p2;
    }
    if (lane == 0) {
      const float scale = 0.125f;
      float mt = fmaxf(fmaxf(lt[0], lt[1]), fmaxf(lt[2], lt[3]));
      float ms = fmaxf(fmaxf(ls[0], ls[1]), fmaxf(ls[2], ls[3]));
      float et[4], es[4], st = 0.f, ss = 0.f;
#pragma unroll
      for (int h = 0; h < 4; ++h) {
        et[h] = __expf((lt[h] - mt) * scale); st += et[h];
        es[h] = __expf((ls[h] - ms) * scale); ss += es[h];
      }
#pragma unroll
      for (int h = 0; h < 4; ++h) {
        at_s[h] = et[h] / st;
        at_s[4 + h] = es[h] / ss;
      }
    }
  }
  __syncthreads();
  float a0 = at_s[0], a1 = at_s[1], a2 = at_s[2], a3 = at_s[3];
  float s0 = at_s[4], s1 = at_s[5], s2 = at_s[6], s3 = at_s[7];
  for (int n = tid; n < 2048; n += 256) {
    float v[10];
#pragma unroll
    for (int c = 0; c < 10; ++c) {
      int o = n * 10 + c;
      v[c] = a0 * V_T[o] + a1 * V_T[20480 + o] + a2 * V_T[40960 + o] + a3 * V_T[61440 + o] +
             s0 * V_S[o] + s1 * V_S[20480 + o] + s2 * V_S[40960 + o] + s3 * V_S[61440 + o];
    }
    uint4 lo, hi;
    lo.x = (unsigned)f2bf(v[0]) | ((unsigned)f2bf(v[1]) << 16);
    lo.y = (unsigned)f2bf(v[2]) | ((unsigned)f2bf(v[3]) << 16);
    lo.z = (unsigned)f2bf(v[4]) | ((unsigned)f2bf(v[5]) << 16);
    lo.w = (unsigned)f2bf(v[6]) | ((unsigned)f2bf(v[7]) << 16);
    hi.x = (unsigned)f2bf(v[8]) | ((unsigned)f2bf(v[9]) << 16);
    hi.y = 0; hi.z = 0; hi.w = 0;
    size_t idx = (size_t)b * 2048 + n;
    *(uint4*)(ets_bf + idx * 16) = lo;
    *(uint4*)(ets_bf + idx * 16 + 8) = hi;
  }
}

// ---------------- phase B: MFMA adjacency + row softmax -> bf16 ----------------

__global__ __launch_bounds__(512, 4) void k_adj(const unsigned short* __restrict__ ets_bf,
                                                const float* __restrict__ dis,
                                                unsigned short* __restrict__ adj) {
  __shared__ __align__(16) unsigned char Bsh[65536];
  __shared__ float st_max[8][16];
  __shared__ float st_sum[8][16];
  __shared__ float rowmax_s[16];
  __shared__ float rowinv_s[16];

  const int tid = threadIdx.x;
  const int lane = tid & 63;
  const int w = tid >> 6;
  const int cl = lane & 15;
  const int g = lane >> 4;
  const int b = blockIdx.x >> 7;
  const int n0 = (blockIdx.x & 127) << 4;

  const unsigned char* gsrc = (const unsigned char*)(ets_bf + (size_t)b * 32768);
#pragma unroll
  for (int it = 0; it < 8; ++it)
    gload16(gsrc + it * 8192 + tid * 16, Bsh + it * 8192 + (w << 10));
  __syncthreads();

  uint4 araw = *(const uint4*)(ets_bf + ((size_t)b * 2048 + n0 + cl) * 16 + (g & 1) * 8);
  if (g >= 2) { araw.x = 0; araw.y = 0; araw.z = 0; araw.w = 0; }
  bf16x8 afrag = __builtin_bit_cast(bf16x8, araw);

  f32x4 acc[16];
  const int cbase = (w << 8) + cl;
#pragma unroll
  for (int n = 0; n < 16; ++n) {
    uint4 braw = *(const uint4*)(Bsh + (size_t)(cbase + n * 16) * 32 + (g & 1) * 16);
    if (g >= 2) { braw.x = 0; braw.y = 0; braw.z = 0; braw.w = 0; }
    bf16x8 bfrag = __builtin_bit_cast(bf16x8, braw);
    acc[n] = __builtin_amdgcn_mfma_f32_16x16x32_bf16(afrag, bfrag, (f32x4){0.f, 0.f, 0.f, 0.f},
                                                     0, 0, 0);
  }

  float mx[4] = {-1e30f, -1e30f, -1e30f, -1e30f};
  const float* dbase = dis + (size_t)(n0 + g * 4) * 2048 + (w << 8) + cl;
#pragma unroll
  for (int n = 0; n < 16; ++n) {
#pragma unroll
    for (int j = 0; j < 4; ++j) {
      float s = fmaxf(acc[n][j] + dbase[(size_t)j * 2048 + n * 16], 0.f);
      acc[n][j] = s;
      mx[j] = fmaxf(mx[j], s);
    }
  }
#pragma unroll
  for (int j = 0; j < 4; ++j) {
    mx[j] = fmaxf(mx[j], __shfl_xor(mx[j], 1));
    mx[j] = fmaxf(mx[j], __shfl_xor(mx[j], 2));
    mx[j] = fmaxf(mx[j], __shfl_xor(mx[j], 4));
    mx[j] = fmaxf(mx[j], __shfl_xor(mx[j], 8));
  }
  if (cl == 0) {
#pragma unroll
    for (int j = 0; j < 4; ++j) st_max[w][g * 4 + j] = mx[j];
  }
  __syncthreads();
  if (tid < 16) {
    float m = st_max[0][tid];
#pragma unroll
    for (int ww = 1; ww < 8; ++ww) m = fmaxf(m, st_max[ww][tid]);
    rowmax_s[tid] = m;
  }
  __syncthreads();

  float rm[4], sm[4] = {0.f, 0.f, 0.f, 0.f};
#pragma unroll
  for (int j = 0; j < 4; ++j) rm[j] = rowmax_s[g * 4 + j];
#pragma unroll
  for (int n = 0; n < 16; ++n) {
#pragma unroll
    for (int j = 0; j < 4; ++j) {
      float e = __expf(acc[n][j] - rm[j]);
      acc[n][j] = e;
      sm[j] += e;
    }
  }
#pragma unroll
  for (int j = 0; j < 4; ++j) {
    sm[j] += __shfl_xor(sm[j], 1);
    sm[j] += __shfl_xor(sm[j], 2);
    sm[j] += __shfl_xor(sm[j], 4);
    sm[j] += __shfl_xor(sm[j], 8);
  }
  if (cl == 0) {
#pragma unroll
    for (int j = 0; j < 4; ++j) st_sum[w][g * 4 + j] = sm[j];
  }
  __syncthreads();
  if (tid < 16) {
    float s = st_sum[0][tid];
#pragma unroll
    for (int ww = 1; ww < 8; ++ww) s += st_sum[ww][tid];
    rowinv_s[tid] = 1.0f / s;
  }
  __syncthreads();

  unsigned short* Tw = (unsigned short*)Bsh + (w << 12);
  float inv[4];
#pragma unroll
  for (int j = 0; j < 4; ++j) inv[j] = rowinv_s[g * 4 + j];
#pragma unroll
  for (int n = 0; n < 16; ++n) {
#pragma unroll
    for (int j = 0; j < 4; ++j)
      Tw[(g * 4 + j) * 256 + n * 16 + cl] = f2bf(acc[n][j] * inv[j]);
  }
  __syncthreads();

  unsigned short* obase = adj + ((size_t)b * 2048 + n0) * 2048 + (w << 8);
#pragma unroll
  for (int r = 0; r < 16; ++r) {
    uint2 v = *(const uint2*)(Tw + r * 256 + lane * 4);
    *(uint2*)(obase + (size_t)r * 2048 + lane * 4) = v;
  }
}

// ---------------- phase C producers ----------------

__device__ __forceinline__ void compute_mat(const float* w, const float* xv, float* out) {
  float4 a[8];
#pragma unroll
  for (int i = 0; i < 8; ++i) a[i] = make_float4(0.f, 0.f, 0.f, 0.f);
#pragma unroll
  for (int k = 0; k < 32; ++k) {
    float xk = xv[k];
#pragma unroll
    for (int d4 = 0; d4 < 8; ++d4) {
      float4 wv = ((const float4*)(w + k * 32))[d4];
      a[d4].x += xk * wv.x; a[d4].y += xk * wv.y; a[d4].z += xk * wv.z; a[d4].w += xk * wv.w;
    }
  }
#pragma unroll
  for (int d4 = 0; d4 < 8; ++d4) {
    out[4 * d4 + 0] = a[d4].x; out[4 * d4 + 1] = a[d4].y;
    out[4 * d4 + 2] = a[d4].z; out[4 * d4 + 3] = a[d4].w;
  }
}

__device__ __forceinline__ void store32bf(unsigned short* p, const float* v) {
#pragma unroll
  for (int i = 0; i < 4; ++i) {
    uint4 u;
    u.x = (unsigned)f2bf(v[8 * i + 0]) | ((unsigned)f2bf(v[8 * i + 1]) << 16);
    u.y = (unsigned)f2bf(v[8 * i + 2]) | ((unsigned)f2bf(v[8 * i + 3]) << 16);
    u.z = (unsigned)f2bf(v[8 * i + 4]) | ((unsigned)f2bf(v[8 * i + 5]) << 16);
    u.w = (unsigned)f2bf(v[8 * i + 6]) | ((unsigned)f2bf(v[8 * i + 7]) << 16);
    ((uint4*)p)[i] = u;
  }
}

__global__ __launch_bounds__(256) void k_zb(const float* __restrict__ x,
                                            const float* __restrict__ W2,
                                            const float* __restrict__ Ws0,
                                            const float* __restrict__ Ws1,
                                            unsigned short* __restrict__ z0T,
                                            unsigned short* __restrict__ bias0,
                                            unsigned short* __restrict__ bias1) {
  __shared__ __align__(16) float w[3][1024];
  int tid = threadIdx.x;
  for (int i = tid; i < 1024; i += 256) {
    w[0][i] = W2[i]; w[1][i] = Ws0[i]; w[2][i] = Ws1[i];
  }
  __syncthreads();
  int bx = blockIdx.x;
  int b = bx / 96, r = bx % 96, t = r >> 3, mc = r & 7;
  int m = (mc << 8) + tid;
  const float4* xp = (const float4*)(x + (((size_t)(b * 2048 + m)) * 12 + t) * 32);
  float xv[32];
#pragma unroll
  for (int i = 0; i < 8; ++i) {
    float4 v = xp[i];
    xv[4 * i + 0] = v.x; xv[4 * i + 1] = v.y; xv[4 * i + 2] = v.z; xv[4 * i + 3] = v.w;
  }
  float out[32];
  compute_mat(w[0], xv, out);
  unsigned short* zp = z0T + (size_t)b * 786432 + (size_t)(t * 32) * 2048 + m;
#pragma unroll
  for (int d = 0; d < 32; ++d) zp[(size_t)d * 2048] = f2bf(out[d]);
  size_t bb = ((size_t)(b * 2048 + m)) * 384 + t * 32;
  compute_mat(w[1], xv, out);
  store32bf(bias0 + bb, out);
  compute_mat(w[2], xv, out);
  store32bf(bias1 + bb, out);
}

// ---------------- phase C: adj @ z (+bias) MFMA GEMM ----------------
// 128x128 tile, BK=32, counted-vmcnt double-buffer, 768 blocks = 3/CU (12 waves/CU)

template <int OUT_F32>
__global__ __launch_bounds__(256, 4) void gemm_adj(const unsigned short* __restrict__ adj,
                                                   const unsigned short* __restrict__ Bt,
                                                   const unsigned short* __restrict__ bias,
                                                   void* __restrict__ outp) {
  const int tid = threadIdx.x;
  const int lane = tid & 63;
  const int wr = (tid >> 7) & 1;
  const int wc = (tid >> 6) & 1;
  // XCD-bijective swizzle: 768 = 8 XCDs x 96; each XCD owns 2 whole batches,
  // consecutive wg cycle the 3 N-tiles of one A-panel (A reuse stays co-XCD)
  const int orig = blockIdx.x;
  const int wg = (orig & 7) * 96 + (orig >> 3);
  const int b = wg / 48;
  const int rem = wg % 48;
  const int m0 = (rem / 3) << 7;
  const int c0 = (rem % 3) << 7;

  // per buffer: A 128x32 (8KB) + B 128x32 (8KB) = 16KB; double = 32KB
  __shared__ __align__(16) unsigned char smem[32768];

  const unsigned short* aBase = adj + ((size_t)b << 22);
  const unsigned short* bBase = Bt + (size_t)b * 786432;
  // staging: thread t -> row t>>2 (+64 for pass 1), chunk (t&3) inverse-swizzled
  // swizzle s(r) = (r>>1)&3 -> zero-conflict 8-slot pattern on ds_read quarter-waves
  const int jx = ((tid & 3) ^ ((tid >> 3) & 3)) << 3;
  const unsigned short* gA = aBase + (size_t)(m0 + (tid >> 2)) * 2048 + jx;
  const unsigned short* gB = bBase + (size_t)(c0 + (tid >> 2)) * 2048 + jx;

  int aoff[4], boff[4];
  {
    const int g = lane >> 4;
#pragma unroll
    for (int f = 0; f < 4; ++f) {
      int rA = wr * 64 + f * 16 + (lane & 15);
      aoff[f] = rA * 64 + ((g ^ ((rA >> 1) & 3)) << 4);
      int rB = wc * 64 + f * 16 + (lane & 15);
      boff[f] = 8192 + rB * 64 + ((g ^ ((rB >> 1) & 3)) << 4);
    }
  }

  f32x4 acc[4][4] = {};

#define STAGE(BUF, KT)                                                      \
  {                                                                         \
    gload16(gA + (KT) * 32, smem + (BUF) + tid * 16);                       \
    gload16(gA + 131072 + (KT) * 32, smem + (BUF) + 4096 + tid * 16);       \
    gload16(gB + (KT) * 32, smem + (BUF) + 8192 + tid * 16);                \
    gload16(gB + 131072 + (KT) * 32, smem + (BUF) + 12288 + tid * 16);      \
  }

  // prologue: tile 0 -> buffer 0
  STAGE(0, 0);

  int cur = 0;
  for (int kt = 0; kt < 64; ++kt) {
    const int nxt = cur ^ 16384;
    if (kt < 63) {
      STAGE(nxt, kt + 1);
      asm volatile("s_waitcnt vmcnt(4)" ::: "memory");  // cur's 4 landed; nxt's 4 in flight
    } else {
      asm volatile("s_waitcnt vmcnt(0)" ::: "memory");
    }
    __builtin_amdgcn_s_barrier();
    bf16x8 af[4], bfv[4];
#pragma unroll
    for (int f = 0; f < 4; ++f) af[f] = *(const bf16x8*)(smem + cur + aoff[f]);
#pragma unroll
    for (int f = 0; f < 4; ++f) bfv[f] = *(const bf16x8*)(smem + cur + boff[f]);
#pragma unroll
    for (int m = 0; m < 4; ++m)
#pragma unroll
      for (int n = 0; n < 4; ++n)
        acc[m][n] = __builtin_amdgcn_mfma_f32_16x16x32_bf16(af[m], bfv[n], acc[m][n], 0, 0, 0);
    __builtin_amdgcn_s_barrier();  // all waves done reading cur before next STAGE overwrites it
    cur = nxt;
  }
#undef STAGE

  const int cl = lane & 15;
  const int r4 = (lane >> 4) << 2;
  const unsigned short* bi = bias + (size_t)b * 786432;
  if (OUT_F32) {
    float* o = (float*)outp + (size_t)b * 786432;
#pragma unroll
    for (int m = 0; m < 4; ++m) {
      int row0 = m0 + wr * 64 + m * 16 + r4;
#pragma unroll
      for (int n = 0; n < 4; ++n) {
        int col = c0 + wc * 64 + n * 16 + cl;
#pragma unroll
        for (int r = 0; r < 4; ++r) {
          int row = row0 + r;
          o[(size_t)row * 384 + col] = acc[m][n][r] + bf2f(bi[(size_t)row * 384 + col]);
        }
      }
    }
  } else {
    unsigned short* o = (unsigned short*)outp + (size_t)b * 786432;
#pragma unroll
    for (int m = 0; m < 4; ++m) {
      int row0 = m0 + wr * 64 + m * 16 + r4;
#pragma unroll
      for (int n = 0; n < 4; ++n) {
        int col = c0 + wc * 64 + n * 16 + cl;
        ushort4 pk;
        pk.x = f2bf(acc[m][n][0] + bf2f(bi[(size_t)(row0 + 0) * 384 + col]));
        pk.y = f2bf(acc[m][n][1] + bf2f(bi[(size_t)(row0 + 1) * 384 + col]));
        pk.z = f2bf(acc[m][n][2] + bf2f(bi[(size_t)(row0 + 2) * 384 + col]));
        pk.w = f2bf(acc[m][n][3] + bf2f(bi[(size_t)(row0 + 3) * 384 + col]));
        *(ushort4*)(o + (size_t)col * 2048 + row0) = pk;
      }
    }
  }
}

// ---------------- launch ----------------

extern "C" void kernel_launch(void* const* d_in, const int* in_sizes, int n_in,
                              void* d_out, int out_size, void* d_ws, size_t ws_size,
                              hipStream_t stream) {
  const float* x = (const float*)d_in[0];
  const float* dis = (const float*)d_in[1];
  const float* K_S = (const float*)d_in[2];
  const float* V_S = (const float*)d_in[3];
  const float* K_T = (const float*)d_in[4];
  const float* V_T = (const float*)d_in[5];
  const float* W_Q0 = (const float*)d_in[6];
  const float* W_QS = (const float*)d_in[7];
  const float* W_QT = (const float*)d_in[8];
  const float* W2 = (const float*)d_in[9];
  const float* W_s0 = (const float*)d_in[10];
  const float* W_s1 = (const float*)d_in[11];

  char* ws = (char*)d_ws;
  float* xmn = (float*)(ws + 0);                             //     24,576 B
  float* pqs = (float*)(ws + 28672);                         //  2,097,152 B
  unsigned short* ets_bf = (unsigned short*)(ws + 2130432);  //  1,048,576 B
  unsigned short* adj = (unsigned short*)(ws + 3179008);     // 134,217,728 B
  unsigned short* z0T = (unsigned short*)(ws + 137396736);   // 25,165,824 B
  unsigned short* z1T = (unsigned short*)(ws + 162562560);   // 25,165,824 B
  unsigned short* bias0 = (unsigned short*)(ws + 187728384); // 25,165,824 B
  unsigned short* bias1 = (unsigned short*)(ws + 212894208); // 25,165,824 B

  k_xmn<<<192, 256, 0, stream>>>(x, xmn);
  k_qs<<<512, 256, 0, stream>>>(x, W_Q0, W_QS, pqs);
  k_post<<<16, 256, 0, stream>>>(pqs, xmn, W_Q0, W_QT, K_T, K_S, V_T, V_S, ets_bf);
  k_adj<<<2048, 512, 0, stream>>>(ets_bf, dis, adj);
  k_zb<<<1536, 256, 0, stream>>>(x, W2, W_s0, W_s1, z0T, bias0, bias1);
  gemm_adj<0><<<768, 256, 0, stream>>>(adj, z0T, bias0, (void*)z1T);
  gemm_adj<1><<<768, 256, 0, stream>>>(adj, z1T, bias1, d_out);
}